// Round 10
// baseline (309.065 us; speedup 1.0000x reference)
//
#include <hip/hip_runtime.h>

#define CDIV(a,b) (((a)+(b)-1)/(b))

typedef _Float16 half4v __attribute__((ext_vector_type(4)));
typedef _Float16 f16x8  __attribute__((ext_vector_type(8)));
typedef unsigned short ushort8v __attribute__((ext_vector_type(8)));
typedef float f32x4 __attribute__((ext_vector_type(4)));

// ---------------- fused prep: zero counts + x->fp16 slice-major + W1^T,W2^T fp16 ----------------
__global__ void prep_kernel(const float* __restrict__ x, _Float16* __restrict__ xs,
                            const float* __restrict__ W1, _Float16* __restrict__ w1t,
                            const float* __restrict__ W2, _Float16* __restrict__ w2t,
                            int* __restrict__ counts,
                            int n, int inc, int hid, int outc) {
    int idx = blockIdx.x * blockDim.x + threadIdx.x;
    int n_xs = n * inc / 8;           // 8 halfs per item
    int n_w1 = inc * hid;
    int n_w2 = hid * outc;
    if (idx < n_xs) {
        int ipn  = inc / 8;           // items per node (32)
        int node = idx / ipn;
        int ch0  = (idx - node * ipn) * 8;
        int s    = ch0 >> 5, wi = ch0 & 31;          // 32-ch slices
        const float4* xp = (const float4*)(x + (size_t)node * inc + ch0);
        float4 a = xp[0], b = xp[1];
        half4v h0, h1;
        h0.x=(_Float16)a.x; h0.y=(_Float16)a.y; h0.z=(_Float16)a.z; h0.w=(_Float16)a.w;
        h1.x=(_Float16)b.x; h1.y=(_Float16)b.y; h1.z=(_Float16)b.z; h1.w=(_Float16)b.w;
        _Float16* dst = xs + ((size_t)s * n + node) * 32 + wi;
        *(half4v*)dst = h0; *(half4v*)(dst + 4) = h1;
    } else if ((idx -= n_xs) < n_w1) {
        int nr = idx / inc, k = idx - nr * inc;      // w1t[nr][k] = W1[k][nr]
        w1t[idx] = (_Float16)W1[(size_t)k * hid + nr];
    } else if ((idx -= n_w1) < n_w2) {
        int nr = idx / hid, k = idx - nr * hid;      // w2t[nr][k] = W2[k][nr]
        w2t[idx] = (_Float16)W2[(size_t)k * outc + nr];
    } else if ((idx -= n_w2) < n) {
        counts[idx] = 0;
    }
}

// ---------------- degree histogram ----------------
__global__ void hist_kernel(const int* __restrict__ coli, int* __restrict__ counts, int E) {
    int e = blockIdx.x * blockDim.x + threadIdx.x;
    if (e < E) atomicAdd(&counts[coli[e]], 1);
}

// ---------------- hierarchical scan: part 1 (block-local inclusive) ----------------
__global__ __launch_bounds__(1024) void scan_part(const int* __restrict__ counts,
                                                  int* __restrict__ offsets,
                                                  int* __restrict__ bsum,
                                                  float* __restrict__ dinv, int n) {
    __shared__ int wsum[16];
    int b = blockIdx.x, tid = threadIdx.x;
    int i = b * 1024 + tid;
    int lane = tid & 63, wid = tid >> 6;
    int v = (i < n) ? counts[i] : 0;
    if (i < n) dinv[i] = 1.0f / sqrtf((float)(v + 1));   // self-loop => deg >= 1
    int x = v;
    #pragma unroll
    for (int off = 1; off < 64; off <<= 1) {
        int t = __shfl_up(x, off);
        if (lane >= off) x += t;
    }
    if (lane == 63) wsum[wid] = x;
    __syncthreads();
    if (tid == 0) {
        int run = 0;
        #pragma unroll
        for (int w = 0; w < 16; ++w) { int t = wsum[w]; wsum[w] = run; run += t; }
        bsum[b] = run;
    }
    __syncthreads();
    int incl = wsum[wid] + x;           // block-local inclusive prefix
    if (i < n) offsets[i + 1] = incl;
}

// ---------------- hierarchical scan: part 2 (add block prefix, emit nexta) ----------------
__global__ __launch_bounds__(1024) void scan_fix(const int* __restrict__ counts,
                                                 int* __restrict__ offsets,
                                                 const int* __restrict__ bsum,
                                                 int* __restrict__ nexta, int n) {
    int b = blockIdx.x, tid = threadIdx.x;
    int i = b * 1024 + tid;
    int pre = 0;
    for (int j = 0; j < b; ++j) pre += bsum[j];   // <=19 uniform loads
    if (i == 0) offsets[0] = 0;
    if (i < n) {
        int incl = offsets[i + 1] + pre;
        offsets[i + 1] = incl;
        nexta[i] = incl - counts[i];              // exclusive prefix = scatter cursor
    }
}

// ---------------- counting-sort scatter (build CSR src lists) ----------------
__global__ void scatter_kernel(const int* __restrict__ rowi, const int* __restrict__ coli,
                               int* __restrict__ nexta, int* __restrict__ srcs, int E) {
    int e = blockIdx.x * blockDim.x + threadIdx.x;
    if (e < E) {
        int c = coli[e];
        int pos = atomicAdd(&nexta[c], 1);
        srcs[pos] = rowi[e];
    }
}

// ---------------- XCD channel-sliced aggregation ----------------
// xs: slice-major fp16 [8][n][8*VEC].  Slice s pinned to XCD via blockIdx%8.
// Wave: 8 edge-groups x 8 lanes; lane loads VEC halfs; cross-group shfl_xor reduce.
// xout row-major [n][64*VEC] (fp16 or fp32).  VEC=4: 256ch.  VEC=2: 128ch.
template<int VEC, bool SARR, typename OUTT>
__global__ __launch_bounds__(256) void agg_sliced(
        const _Float16* __restrict__ xs, const int* __restrict__ srcs,
        const int* __restrict__ offsets, const float* __restrict__ dinv,
        OUTT* __restrict__ xout, float* __restrict__ sarr, int n) {
    constexpr int RS = 8 * VEC;          // halfs per slice-row
    constexpr int C  = 8 * RS;           // total channels
    typedef _Float16 hv __attribute__((ext_vector_type(VEC)));
    typedef float    fv __attribute__((ext_vector_type(VEC)));
    int wid  = threadIdx.x >> 6, lane = threadIdx.x & 63;
    int s    = blockIdx.x & 7;
    int c    = (blockIdx.x >> 3) * 4 + wid;
    if (c >= n) return;
    int g    = lane >> 3, t = lane & 7;
    int beg  = __builtin_amdgcn_readfirstlane(offsets[c]);       // wave-uniform scalar bounds
    int end  = __builtin_amdgcn_readfirstlane(offsets[c + 1]);
    const _Float16* tab = xs + (size_t)s * n * RS;
    float acc[VEC] = {};
    float wsum = 0.f;
    for (int i = beg; i < end; i += 8) {          // 8 edges in flight per wave
        int  e   = i + g;
        bool val = e < end;
        int  r   = val ? srcs[e] : c;             // srcs padded +8 ints
        float w  = val ? dinv[r] : 0.f;
        hv v = *(const hv*)(tab + (size_t)r * RS + t * VEC);
        #pragma unroll
        for (int k = 0; k < VEC; ++k) acc[k] = fmaf(w, (float)v[k], acc[k]);
        wsum += w;
    }
    float dc = dinv[c];
    if (g == 0) {                                 // self-loop counted once
        hv vc = *(const hv*)(tab + (size_t)c * RS + t * VEC);
        #pragma unroll
        for (int k = 0; k < VEC; ++k) acc[k] = fmaf(dc, (float)vc[k], acc[k]);
        wsum += dc;
    }
    #pragma unroll
    for (int off = 8; off < 64; off <<= 1) {      // reduce over 8 groups
        #pragma unroll
        for (int k = 0; k < VEC; ++k) acc[k] += __shfl_xor(acc[k], off);
        wsum += __shfl_xor(wsum, off);
    }
    if (g == 0) {
        if constexpr (sizeof(OUTT) == 2) {
            hv o;
            #pragma unroll
            for (int k = 0; k < VEC; ++k) o[k] = (_Float16)(acc[k] * dc);
            *(hv*)((_Float16*)xout + (size_t)c * C + s * RS + t * VEC) = o;
        } else {
            fv o;
            #pragma unroll
            for (int k = 0; k < VEC; ++k) o[k] = acc[k] * dc;
            *(fv*)((float*)xout + (size_t)c * C + s * RS + t * VEC) = o;
        }
        if (SARR && s == 0 && lane == 0) sarr[c] = dc * wsum;
    }
}

// ---------------- fp16 MFMA GEMM: C = A@B (+ bias or s*bias) (+relu), fp16 out ----------------
// A: MxK f16 row-major.  BT: NxK f16 row-major.  C: row-major, or 16-ch slice-major [N/16][tabn][16].
template<int BM, int BN, bool RELU, bool SBIAS, bool SLICED>
__global__ __launch_bounds__(256) void gemm_mfma(
        const _Float16* __restrict__ A, const _Float16* __restrict__ BT,
        const float* __restrict__ bias, const float* __restrict__ sarr,
        _Float16* __restrict__ C, int M, int K, int N, int tabn) {
    constexpr int FM = BM / 2 / 16, FN = BN / 2 / 16;
    constexpr int APT = BM * 4 / 256, BPT = BN * 4 / 256;   // 16B granules per thread
    static_assert(BM % 32 == 0 && BN % 32 == 0, "wave tile divisibility");
    __shared__ unsigned short A_lds[BM * 40];   // 80 B per 32-half row (2-way bank aliasing, free)
    __shared__ unsigned short B_lds[BN * 40];
    int tid  = threadIdx.x;
    int wid  = tid >> 6, lane = tid & 63;
    int wm   = wid >> 1, wn = wid & 1;
    int q    = lane >> 4, r = lane & 15;
    int m0   = blockIdx.x * BM, n0 = blockIdx.y * BN;

    f32x4 acc[FM][FN];
    #pragma unroll
    for (int i = 0; i < FM; ++i)
        #pragma unroll
        for (int j = 0; j < FN; ++j)
            acc[i][j] = (f32x4){0.f, 0.f, 0.f, 0.f};

    ushort8v areg[APT], breg[BPT];
    auto loadA = [&](int k0) {
        #pragma unroll
        for (int i = 0; i < APT; ++i) {
            int g = tid + i * 256;
            int row = g >> 2, slot = g & 3;
            int gm = m0 + row;
            if (gm < M) areg[i] = *(const ushort8v*)(A + (size_t)gm * K + k0 + slot * 8);
            else        areg[i] = (ushort8v){0,0,0,0,0,0,0,0};
        }
    };
    auto loadB = [&](int k0) {
        #pragma unroll
        for (int i = 0; i < BPT; ++i) {
            int g = tid + i * 256;
            int row = g >> 2, slot = g & 3;
            breg[i] = *(const ushort8v*)(BT + (size_t)(n0 + row) * K + k0 + slot * 8);
        }
    };

    loadA(0); loadB(0);
    int steps = K / 32;
    for (int s = 0; s < steps; ++s) {
        __syncthreads();
        #pragma unroll
        for (int i = 0; i < APT; ++i) {
            int g = tid + i * 256;
            *(ushort8v*)&A_lds[(g >> 2) * 40 + (g & 3) * 8] = areg[i];
        }
        #pragma unroll
        for (int i = 0; i < BPT; ++i) {
            int g = tid + i * 256;
            *(ushort8v*)&B_lds[(g >> 2) * 40 + (g & 3) * 8] = breg[i];
        }
        __syncthreads();
        if (s + 1 < steps) { loadA((s + 1) * 32); loadB((s + 1) * 32); }
        f16x8 af[FM], bf[FN];
        #pragma unroll
        for (int i = 0; i < FM; ++i)
            af[i] = *(const f16x8*)&A_lds[(wm * (BM / 2) + i * 16 + r) * 40 + q * 8];
        #pragma unroll
        for (int j = 0; j < FN; ++j)
            bf[j] = *(const f16x8*)&B_lds[(wn * (BN / 2) + j * 16 + r) * 40 + q * 8];
        #pragma unroll
        for (int i = 0; i < FM; ++i)
            #pragma unroll
            for (int j = 0; j < FN; ++j)
                acc[i][j] = __builtin_amdgcn_mfma_f32_16x16x32_f16(af[i], bf[j], acc[i][j], 0, 0, 0);
    }

    // epilogue: D row = q*4+reg, col = r (m89-verified layout)
    #pragma unroll
    for (int i = 0; i < FM; ++i) {
        int row_base = m0 + wm * (BM / 2) + i * 16 + q * 4;
        #pragma unroll
        for (int g = 0; g < 4; ++g) {
            int row = row_base + g;
            if (row >= M) continue;
            float sv = SBIAS ? sarr[row] : 1.f;
            #pragma unroll
            for (int j = 0; j < FN; ++j) {
                int col = n0 + wn * (BN / 2) + j * 16 + r;
                float v = acc[i][j][g] + sv * bias[col];
                if (RELU) v = fmaxf(v, 0.f);
                size_t addr = SLICED ? ((size_t)(col >> 4) * tabn + row) * 16 + (col & 15)
                                     : (size_t)row * N + col;
                C[addr] = (_Float16)v;
            }
        }
    }
}

extern "C" void kernel_launch(void* const* d_in, const int* in_sizes, int n_in,
                              void* d_out, int out_size, void* d_ws, size_t ws_size,
                              hipStream_t stream) {
    const float* x  = (const float*)d_in[0];
    const int*   ei = (const int*)d_in[1];
    const float* W1 = (const float*)d_in[2];
    const float* b1 = (const float*)d_in[3];
    const float* W2 = (const float*)d_in[4];
    const float* b2 = (const float*)d_in[5];

    const int hid  = in_sizes[3];             // 512
    const int outc = in_sizes[5];             // 128
    const int inc  = in_sizes[2] / hid;       // 256
    const int n    = in_sizes[0] / inc;       // 20000
    const int E    = in_sizes[1] / 2;         // 640000
    const int* rowi = ei;                     // edge_index[0] = sources
    const int* coli = ei + E;                 // edge_index[1] = destinations

    char* p = (char*)d_ws;
    auto carve = [&](size_t bytes) {
        char* q = p;
        p += (bytes + 255) & ~(size_t)255;
        return (void*)q;
    };
    int*      counts  = (int*)     carve((size_t)n * 4);
    int*      offsets = (int*)     carve((size_t)(n + 1) * 4);
    int*      nexta   = (int*)     carve((size_t)n * 4);
    int*      srcs    = (int*)     carve((size_t)(E + 8) * 4);   // +8 pad for guarded tail loads
    float*    dinv    = (float*)   carve((size_t)n * 4);
    float*    sarr    = (float*)   carve((size_t)n * 4);
    int*      bsum    = (int*)     carve((size_t)32 * 4);
    _Float16* xs      = (_Float16*)carve((size_t)n * inc * 2);   // fp16 x, 32-ch slice-major (reused as zs)
    _Float16* aggxh   = (_Float16*)carve((size_t)n * inc * 2);   // fp16 A@x, row-major
    _Float16* hh      = (_Float16*)carve((size_t)n * hid * 2);   // fp16 hidden, row-major
    _Float16* w1t     = (_Float16*)carve((size_t)inc * hid * 2); // fp16 W1^T [hid][inc]
    _Float16* w2t     = (_Float16*)carve((size_t)hid * outc * 2);// fp16 W2^T [outc][hid]
    _Float16* zs      = xs;                                       // alias: xs dead after agg1

    const int SCAN_B = CDIV(n, 1024);
    const int PREP_T = n * inc / 8 + inc * hid + hid * outc + n;

    prep_kernel<<<CDIV(PREP_T, 256), 256, 0, stream>>>(x, xs, W1, w1t, W2, w2t, counts,
                                                       n, inc, hid, outc);
    hist_kernel<<<CDIV(E, 256), 256, 0, stream>>>(coli, counts, E);
    scan_part<<<SCAN_B, 1024, 0, stream>>>(counts, offsets, bsum, dinv, n);
    scan_fix<<<SCAN_B, 1024, 0, stream>>>(counts, offsets, bsum, nexta, n);
    scatter_kernel<<<CDIV(E, 256), 256, 0, stream>>>(rowi, coli, nexta, srcs, E);

    // layer 1: h = relu((A@x) @ W1 + s*b1)
    agg_sliced<4, true, _Float16><<<CDIV(n, 4) * 8, 256, 0, stream>>>(
        xs, srcs, offsets, dinv, aggxh, sarr, n);
    dim3 g1(CDIV(n, 128), hid / 128);
    gemm_mfma<128, 128, true, true, false><<<g1, 256, 0, stream>>>(
        aggxh, w1t, b1, sarr, hh, n, inc, hid, 0);

    // layer 2: out = A@(h @ W2 + b2), z written 16-ch slice-major
    dim3 g2(CDIV(n, 64), outc / 128);
    gemm_mfma<64, 128, false, false, true><<<g2, 256, 0, stream>>>(
        hh, w2t, b2, nullptr, zs, n, hid, outc, n);
    agg_sliced<2, false, float><<<CDIV(n, 4) * 8, 256, 0, stream>>>(
        zs, srcs, offsets, dinv, (float*)d_out, nullptr, n);
}

// Round 12
// 237.116 us; speedup vs baseline: 1.3034x; 1.3034x over previous
//
#include <hip/hip_runtime.h>

#define CDIV(a,b) (((a)+(b)-1)/(b))

typedef _Float16 half4v __attribute__((ext_vector_type(4)));
typedef _Float16 half2v __attribute__((ext_vector_type(2)));
typedef _Float16 f16x8  __attribute__((ext_vector_type(8)));
typedef unsigned short ushort8v __attribute__((ext_vector_type(8)));
typedef float f32x4 __attribute__((ext_vector_type(4)));

// ---------------- fused prep: x->fp16 row-major + W1^T,W2^T fp16 + zero counts ----------------
__global__ void prep_kernel(const float* __restrict__ x, _Float16* __restrict__ xh,
                            const float* __restrict__ W1, _Float16* __restrict__ w1t,
                            const float* __restrict__ W2, _Float16* __restrict__ w2t,
                            int* __restrict__ counts,
                            int n, int inc, int hid, int outc) {
    int idx = blockIdx.x * blockDim.x + threadIdx.x;
    int n_xh = n * inc / 8;           // 8 halfs per item, row-major linear
    int n_w1 = inc * hid;
    int n_w2 = hid * outc;
    if (idx < n_xh) {
        const float4* xp = (const float4*)(x + (size_t)idx * 8);
        float4 a = xp[0], b = xp[1];
        half4v h0, h1;
        h0.x=(_Float16)a.x; h0.y=(_Float16)a.y; h0.z=(_Float16)a.z; h0.w=(_Float16)a.w;
        h1.x=(_Float16)b.x; h1.y=(_Float16)b.y; h1.z=(_Float16)b.z; h1.w=(_Float16)b.w;
        _Float16* dst = xh + (size_t)idx * 8;
        *(half4v*)dst = h0; *(half4v*)(dst + 4) = h1;
    } else if ((idx -= n_xh) < n_w1) {
        int nr = idx / inc, k = idx - nr * inc;      // w1t[nr][k] = W1[k][nr]
        w1t[idx] = (_Float16)W1[(size_t)k * hid + nr];
    } else if ((idx -= n_w1) < n_w2) {
        int nr = idx / hid, k = idx - nr * hid;      // w2t[nr][k] = W2[k][nr]
        w2t[idx] = (_Float16)W2[(size_t)k * outc + nr];
    } else if ((idx -= n_w2) < n) {
        counts[idx] = 0;
    }
}

// ---------------- degree histogram ----------------
__global__ void hist_kernel(const int* __restrict__ coli, int* __restrict__ counts, int E) {
    int e = blockIdx.x * blockDim.x + threadIdx.x;
    if (e < E) atomicAdd(&counts[coli[e]], 1);
}

// ---------------- hierarchical scan: part 1 (block-local inclusive) ----------------
__global__ __launch_bounds__(1024) void scan_part(const int* __restrict__ counts,
                                                  int* __restrict__ offsets,
                                                  int* __restrict__ bsum,
                                                  float* __restrict__ dinv, int n) {
    __shared__ int wsum[16];
    int b = blockIdx.x, tid = threadIdx.x;
    int i = b * 1024 + tid;
    int lane = tid & 63, wid = tid >> 6;
    int v = (i < n) ? counts[i] : 0;
    if (i < n) dinv[i] = 1.0f / sqrtf((float)(v + 1));   // self-loop => deg >= 1
    int x = v;
    #pragma unroll
    for (int off = 1; off < 64; off <<= 1) {
        int t = __shfl_up(x, off);
        if (lane >= off) x += t;
    }
    if (lane == 63) wsum[wid] = x;
    __syncthreads();
    if (tid == 0) {
        int run = 0;
        #pragma unroll
        for (int w = 0; w < 16; ++w) { int t = wsum[w]; wsum[w] = run; run += t; }
        bsum[b] = run;
    }
    __syncthreads();
    int incl = wsum[wid] + x;           // block-local inclusive prefix
    if (i < n) offsets[i + 1] = incl;
}

// ---------------- hierarchical scan: part 2 (add block prefix, emit nexta) ----------------
__global__ __launch_bounds__(1024) void scan_fix(const int* __restrict__ counts,
                                                 int* __restrict__ offsets,
                                                 const int* __restrict__ bsum,
                                                 int* __restrict__ nexta, int n) {
    int b = blockIdx.x, tid = threadIdx.x;
    int i = b * 1024 + tid;
    int pre = 0;
    for (int j = 0; j < b; ++j) pre += bsum[j];   // <=19 uniform loads
    if (i == 0) offsets[0] = 0;
    if (i < n) {
        int incl = offsets[i + 1] + pre;
        offsets[i + 1] = incl;
        nexta[i] = incl - counts[i];              // exclusive prefix = scatter cursor
    }
}

// ---------------- counting-sort scatter (build CSR src lists) ----------------
__global__ void scatter_kernel(const int* __restrict__ rowi, const int* __restrict__ coli,
                               int* __restrict__ nexta, int* __restrict__ srcs, int E) {
    int e = blockIdx.x * blockDim.x + threadIdx.x;
    if (e < E) {
        int c = coli[e];
        int pos = atomicAdd(&nexta[c], 1);
        srcs[pos] = rowi[e];
    }
}

// ---------------- layer-1 aggregation: fp16 gather (256 ch), fp32 accum, fp16 out ----------------
// 1 wave per destination, lane = half4 (8 B, coalesced 512B/row), 4x edge unroll.
__global__ void agg1_f16(const _Float16* __restrict__ xh, const int* __restrict__ srcs,
                         const int* __restrict__ offsets, const float* __restrict__ dinv,
                         _Float16* __restrict__ xout, float* __restrict__ sarr,
                         int vpr, int n) {
    int gw   = blockIdx.x * (blockDim.x >> 6) + (threadIdx.x >> 6);
    int lane = threadIdx.x & 63;
    if (gw >= n) return;
    int c   = __builtin_amdgcn_readfirstlane(gw);
    int beg = __builtin_amdgcn_readfirstlane(offsets[c]);
    int end = __builtin_amdgcn_readfirstlane(offsets[c + 1]);
    const half4v* x4 = (const half4v*)xh;
    float4 acc = make_float4(0.f, 0.f, 0.f, 0.f);
    float wsum = 0.f;
    int i = beg;
    for (; i + 3 < end; i += 4) {
        int r0 = __builtin_amdgcn_readfirstlane(srcs[i + 0]);
        int r1 = __builtin_amdgcn_readfirstlane(srcs[i + 1]);
        int r2 = __builtin_amdgcn_readfirstlane(srcs[i + 2]);
        int r3 = __builtin_amdgcn_readfirstlane(srcs[i + 3]);
        float w0 = dinv[r0], w1 = dinv[r1], w2 = dinv[r2], w3 = dinv[r3];
        half4v v0 = x4[(size_t)r0 * vpr + lane];
        half4v v1 = x4[(size_t)r1 * vpr + lane];
        half4v v2 = x4[(size_t)r2 * vpr + lane];
        half4v v3 = x4[(size_t)r3 * vpr + lane];
        acc.x = fmaf(w0, (float)v0.x, acc.x); acc.y = fmaf(w0, (float)v0.y, acc.y);
        acc.z = fmaf(w0, (float)v0.z, acc.z); acc.w = fmaf(w0, (float)v0.w, acc.w);
        acc.x = fmaf(w1, (float)v1.x, acc.x); acc.y = fmaf(w1, (float)v1.y, acc.y);
        acc.z = fmaf(w1, (float)v1.z, acc.z); acc.w = fmaf(w1, (float)v1.w, acc.w);
        acc.x = fmaf(w2, (float)v2.x, acc.x); acc.y = fmaf(w2, (float)v2.y, acc.y);
        acc.z = fmaf(w2, (float)v2.z, acc.z); acc.w = fmaf(w2, (float)v2.w, acc.w);
        acc.x = fmaf(w3, (float)v3.x, acc.x); acc.y = fmaf(w3, (float)v3.y, acc.y);
        acc.z = fmaf(w3, (float)v3.z, acc.z); acc.w = fmaf(w3, (float)v3.w, acc.w);
        wsum += w0 + w1 + w2 + w3;
    }
    for (; i < end; ++i) {
        int r   = __builtin_amdgcn_readfirstlane(srcs[i]);
        float w = dinv[r];
        half4v v = x4[(size_t)r * vpr + lane];
        acc.x = fmaf(w, (float)v.x, acc.x); acc.y = fmaf(w, (float)v.y, acc.y);
        acc.z = fmaf(w, (float)v.z, acc.z); acc.w = fmaf(w, (float)v.w, acc.w);
        wsum += w;
    }
    float dc = dinv[c];
    half4v vc = x4[(size_t)c * vpr + lane];
    acc.x = fmaf(dc, (float)vc.x, acc.x); acc.y = fmaf(dc, (float)vc.y, acc.y);
    acc.z = fmaf(dc, (float)vc.z, acc.z); acc.w = fmaf(dc, (float)vc.w, acc.w);
    wsum += dc;
    half4v o;
    o.x = (_Float16)(acc.x * dc); o.y = (_Float16)(acc.y * dc);
    o.z = (_Float16)(acc.z * dc); o.w = (_Float16)(acc.w * dc);
    ((half4v*)xout)[(size_t)c * vpr + lane] = o;
    if (sarr && lane == 0) sarr[c] = dc * wsum;   // s = rowsum of A_norm
}

// ---------------- layer-2 aggregation: fp16 gather (128 ch), fp32 out ----------------
__global__ void agg2_f16(const _Float16* __restrict__ zh, const int* __restrict__ srcs,
                         const int* __restrict__ offsets, const float* __restrict__ dinv,
                         float* __restrict__ xout, int vpr, int n) {
    int gw   = blockIdx.x * (blockDim.x >> 6) + (threadIdx.x >> 6);
    int lane = threadIdx.x & 63;
    if (gw >= n) return;
    int c   = __builtin_amdgcn_readfirstlane(gw);
    int beg = __builtin_amdgcn_readfirstlane(offsets[c]);
    int end = __builtin_amdgcn_readfirstlane(offsets[c + 1]);
    const half2v* x2 = (const half2v*)zh;
    float2 acc = make_float2(0.f, 0.f);
    int i = beg;
    for (; i + 3 < end; i += 4) {
        int r0 = __builtin_amdgcn_readfirstlane(srcs[i + 0]);
        int r1 = __builtin_amdgcn_readfirstlane(srcs[i + 1]);
        int r2 = __builtin_amdgcn_readfirstlane(srcs[i + 2]);
        int r3 = __builtin_amdgcn_readfirstlane(srcs[i + 3]);
        float w0 = dinv[r0], w1 = dinv[r1], w2 = dinv[r2], w3 = dinv[r3];
        half2v v0 = x2[(size_t)r0 * vpr + lane];
        half2v v1 = x2[(size_t)r1 * vpr + lane];
        half2v v2 = x2[(size_t)r2 * vpr + lane];
        half2v v3 = x2[(size_t)r3 * vpr + lane];
        acc.x = fmaf(w0, (float)v0.x, acc.x); acc.y = fmaf(w0, (float)v0.y, acc.y);
        acc.x = fmaf(w1, (float)v1.x, acc.x); acc.y = fmaf(w1, (float)v1.y, acc.y);
        acc.x = fmaf(w2, (float)v2.x, acc.x); acc.y = fmaf(w2, (float)v2.y, acc.y);
        acc.x = fmaf(w3, (float)v3.x, acc.x); acc.y = fmaf(w3, (float)v3.y, acc.y);
    }
    for (; i < end; ++i) {
        int r   = __builtin_amdgcn_readfirstlane(srcs[i]);
        float w = dinv[r];
        half2v v = x2[(size_t)r * vpr + lane];
        acc.x = fmaf(w, (float)v.x, acc.x); acc.y = fmaf(w, (float)v.y, acc.y);
    }
    float dc = dinv[c];
    half2v vc = x2[(size_t)c * vpr + lane];
    acc.x = fmaf(dc, (float)vc.x, acc.x); acc.y = fmaf(dc, (float)vc.y, acc.y);
    acc.x *= dc; acc.y *= dc;
    ((float2*)xout)[(size_t)c * vpr + lane] = acc;
}

// ---------------- fp16 MFMA GEMM: C = A@B (+ bias or s*bias) (+relu), fp16 out ----------------
// A: MxK f16 row-major.  BT: NxK f16 row-major.  C: MxN f16 row-major.
template<int BM, int BN, bool RELU, bool SBIAS>
__global__ __launch_bounds__(256) void gemm_mfma(
        const _Float16* __restrict__ A, const _Float16* __restrict__ BT,
        const float* __restrict__ bias, const float* __restrict__ sarr,
        _Float16* __restrict__ C, int M, int K, int N) {
    constexpr int FM = BM / 2 / 16, FN = BN / 2 / 16;
    constexpr int APT = BM * 4 / 256, BPT = BN * 4 / 256;   // 16B granules per thread
    static_assert(BM % 32 == 0 && BN % 32 == 0, "wave tile divisibility");
    __shared__ unsigned short A_lds[BM * 40];   // 80 B per 32-half row (2-way bank aliasing, free)
    __shared__ unsigned short B_lds[BN * 40];
    int tid  = threadIdx.x;
    int wid  = tid >> 6, lane = tid & 63;
    int wm   = wid >> 1, wn = wid & 1;
    int q    = lane >> 4, r = lane & 15;
    int m0   = blockIdx.x * BM, n0 = blockIdx.y * BN;

    f32x4 acc[FM][FN];
    #pragma unroll
    for (int i = 0; i < FM; ++i)
        #pragma unroll
        for (int j = 0; j < FN; ++j)
            acc[i][j] = (f32x4){0.f, 0.f, 0.f, 0.f};

    ushort8v areg[APT], breg[BPT];
    auto loadA = [&](int k0) {
        #pragma unroll
        for (int i = 0; i < APT; ++i) {
            int g = tid + i * 256;
            int row = g >> 2, slot = g & 3;
            int gm = m0 + row;
            if (gm < M) areg[i] = *(const ushort8v*)(A + (size_t)gm * K + k0 + slot * 8);
            else        areg[i] = (ushort8v){0,0,0,0,0,0,0,0};
        }
    };
    auto loadB = [&](int k0) {
        #pragma unroll
        for (int i = 0; i < BPT; ++i) {
            int g = tid + i * 256;
            int row = g >> 2, slot = g & 3;
            breg[i] = *(const ushort8v*)(BT + (size_t)(n0 + row) * K + k0 + slot * 8);
        }
    };

    loadA(0); loadB(0);
    int steps = K / 32;
    for (int s = 0; s < steps; ++s) {
        __syncthreads();
        #pragma unroll
        for (int i = 0; i < APT; ++i) {
            int g = tid + i * 256;
            *(ushort8v*)&A_lds[(g >> 2) * 40 + (g & 3) * 8] = areg[i];
        }
        #pragma unroll
        for (int i = 0; i < BPT; ++i) {
            int g = tid + i * 256;
            *(ushort8v*)&B_lds[(g >> 2) * 40 + (g & 3) * 8] = breg[i];
        }
        __syncthreads();
        if (s + 1 < steps) { loadA((s + 1) * 32); loadB((s + 1) * 32); }
        f16x8 af[FM], bf[FN];
        #pragma unroll
        for (int i = 0; i < FM; ++i)
            af[i] = *(const f16x8*)&A_lds[(wm * (BM / 2) + i * 16 + r) * 40 + q * 8];
        #pragma unroll
        for (int j = 0; j < FN; ++j)
            bf[j] = *(const f16x8*)&B_lds[(wn * (BN / 2) + j * 16 + r) * 40 + q * 8];
        #pragma unroll
        for (int i = 0; i < FM; ++i)
            #pragma unroll
            for (int j = 0; j < FN; ++j)
                acc[i][j] = __builtin_amdgcn_mfma_f32_16x16x32_f16(af[i], bf[j], acc[i][j], 0, 0, 0);
    }

    // epilogue: D row = q*4+reg, col = r (m89-verified layout)
    #pragma unroll
    for (int i = 0; i < FM; ++i) {
        int row_base = m0 + wm * (BM / 2) + i * 16 + q * 4;
        #pragma unroll
        for (int g = 0; g < 4; ++g) {
            int row = row_base + g;
            if (row >= M) continue;
            float sv = SBIAS ? sarr[row] : 1.f;
            #pragma unroll
            for (int j = 0; j < FN; ++j) {
                int col = n0 + wn * (BN / 2) + j * 16 + r;
                float v = acc[i][j][g] + sv * bias[col];
                if (RELU) v = fmaxf(v, 0.f);
                C[(size_t)row * N + col] = (_Float16)v;
            }
        }
    }
}

extern "C" void kernel_launch(void* const* d_in, const int* in_sizes, int n_in,
                              void* d_out, int out_size, void* d_ws, size_t ws_size,
                              hipStream_t stream) {
    const float* x  = (const float*)d_in[0];
    const int*   ei = (const int*)d_in[1];
    const float* W1 = (const float*)d_in[2];
    const float* b1 = (const float*)d_in[3];
    const float* W2 = (const float*)d_in[4];
    const float* b2 = (const float*)d_in[5];

    const int hid  = in_sizes[3];             // 512
    const int outc = in_sizes[5];             // 128
    const int inc  = in_sizes[2] / hid;       // 256
    const int n    = in_sizes[0] / inc;       // 20000
    const int E    = in_sizes[1] / 2;         // 640000
    const int* rowi = ei;                     // edge_index[0] = sources
    const int* coli = ei + E;                 // edge_index[1] = destinations

    char* p = (char*)d_ws;
    auto carve = [&](size_t bytes) {
        char* q = p;
        p += (bytes + 255) & ~(size_t)255;
        return (void*)q;
    };
    int*      counts  = (int*)     carve((size_t)n * 4);
    int*      offsets = (int*)     carve((size_t)(n + 1) * 4);
    int*      nexta   = (int*)     carve((size_t)n * 4);
    int*      srcs    = (int*)     carve((size_t)(E + 8) * 4);
    float*    dinv    = (float*)   carve((size_t)n * 4);
    float*    sarr    = (float*)   carve((size_t)n * 4);
    int*      bsum    = (int*)     carve((size_t)32 * 4);
    _Float16* xh      = (_Float16*)carve((size_t)n * inc * 2);   // fp16 x row-major (reused as zh)
    _Float16* aggxh   = (_Float16*)carve((size_t)n * inc * 2);   // fp16 A@x row-major
    _Float16* hh      = (_Float16*)carve((size_t)n * hid * 2);   // fp16 hidden row-major
    _Float16* w1t     = (_Float16*)carve((size_t)inc * hid * 2); // fp16 W1^T [hid][inc]
    _Float16* w2t     = (_Float16*)carve((size_t)hid * outc * 2);// fp16 W2^T [outc][hid]
    _Float16* zh      = xh;                                       // alias: xh dead after agg1

    const int SCAN_B = CDIV(n, 1024);
    const int PREP_T = n * inc / 8 + inc * hid + hid * outc + n;

    prep_kernel<<<CDIV(PREP_T, 256), 256, 0, stream>>>(x, xh, W1, w1t, W2, w2t, counts,
                                                       n, inc, hid, outc);
    hist_kernel<<<CDIV(E, 256), 256, 0, stream>>>(coli, counts, E);
    scan_part<<<SCAN_B, 1024, 0, stream>>>(counts, offsets, bsum, dinv, n);
    scan_fix<<<SCAN_B, 1024, 0, stream>>>(counts, offsets, bsum, nexta, n);
    scatter_kernel<<<CDIV(E, 256), 256, 0, stream>>>(rowi, coli, nexta, srcs, E);

    // layer 1: h = relu((A@x) @ W1 + s*b1)
    agg1_f16<<<CDIV(n, 4), 256, 0, stream>>>(xh, srcs, offsets, dinv, aggxh, sarr, inc / 4, n);
    dim3 g1(CDIV(n, 128), hid / 128);
    gemm_mfma<128, 128, true, true><<<g1, 256, 0, stream>>>(aggxh, w1t, b1, sarr, hh, n, inc, hid);

    // layer 2: out = A@(h @ W2 + b2)
    dim3 g2(CDIV(n, 64), outc / 128);
    gemm_mfma<64, 128, false, false><<<g2, 256, 0, stream>>>(hh, w2t, b2, nullptr, zh, n, hid, outc);
    agg2_f16<<<CDIV(n, 4), 256, 0, stream>>>(zh, srcs, offsets, dinv, (float*)d_out, outc / 2, n);
}

// Round 13
// 232.881 us; speedup vs baseline: 1.3271x; 1.0182x over previous
//
#include <hip/hip_runtime.h>

#define CDIV(a,b) (((a)+(b)-1)/(b))

typedef _Float16 half4v __attribute__((ext_vector_type(4)));
typedef _Float16 half2v __attribute__((ext_vector_type(2)));
typedef _Float16 f16x8  __attribute__((ext_vector_type(8)));
typedef unsigned short ushort8v __attribute__((ext_vector_type(8)));
typedef float f32x4 __attribute__((ext_vector_type(4)));

#define RL(x) __builtin_amdgcn_readfirstlane(x)

// ---------------- fused prep: x->fp16 row-major + W1^T,W2^T fp16 + zero counts ----------------
__global__ void prep_kernel(const float* __restrict__ x, _Float16* __restrict__ xh,
                            const float* __restrict__ W1, _Float16* __restrict__ w1t,
                            const float* __restrict__ W2, _Float16* __restrict__ w2t,
                            int* __restrict__ counts,
                            int n, int inc, int hid, int outc) {
    int idx = blockIdx.x * blockDim.x + threadIdx.x;
    int n_xh = n * inc / 8;           // 8 halfs per item, row-major linear
    int n_w1 = inc * hid;
    int n_w2 = hid * outc;
    if (idx < n_xh) {
        const float4* xp = (const float4*)(x + (size_t)idx * 8);
        float4 a = xp[0], b = xp[1];
        half4v h0, h1;
        h0.x=(_Float16)a.x; h0.y=(_Float16)a.y; h0.z=(_Float16)a.z; h0.w=(_Float16)a.w;
        h1.x=(_Float16)b.x; h1.y=(_Float16)b.y; h1.z=(_Float16)b.z; h1.w=(_Float16)b.w;
        _Float16* dst = xh + (size_t)idx * 8;
        *(half4v*)dst = h0; *(half4v*)(dst + 4) = h1;
    } else if ((idx -= n_xh) < n_w1) {
        int nr = idx / inc, k = idx - nr * inc;      // w1t[nr][k] = W1[k][nr]
        w1t[idx] = (_Float16)W1[(size_t)k * hid + nr];
    } else if ((idx -= n_w1) < n_w2) {
        int nr = idx / hid, k = idx - nr * hid;      // w2t[nr][k] = W2[k][nr]
        w2t[idx] = (_Float16)W2[(size_t)k * outc + nr];
    } else if ((idx -= n_w2) < n) {
        counts[idx] = 0;
    }
}

// ---------------- degree histogram ----------------
__global__ void hist_kernel(const int* __restrict__ coli, int* __restrict__ counts, int E) {
    int e = blockIdx.x * blockDim.x + threadIdx.x;
    if (e < E) atomicAdd(&counts[coli[e]], 1);
}

// ---------------- hierarchical scan: part 1 (block-local inclusive) ----------------
__global__ __launch_bounds__(1024) void scan_part(const int* __restrict__ counts,
                                                  int* __restrict__ offsets,
                                                  int* __restrict__ bsum,
                                                  float* __restrict__ dinv, int n) {
    __shared__ int wsum[16];
    int b = blockIdx.x, tid = threadIdx.x;
    int i = b * 1024 + tid;
    int lane = tid & 63, wid = tid >> 6;
    int v = (i < n) ? counts[i] : 0;
    if (i < n) dinv[i] = 1.0f / sqrtf((float)(v + 1));   // self-loop => deg >= 1
    int x = v;
    #pragma unroll
    for (int off = 1; off < 64; off <<= 1) {
        int t = __shfl_up(x, off);
        if (lane >= off) x += t;
    }
    if (lane == 63) wsum[wid] = x;
    __syncthreads();
    if (tid == 0) {
        int run = 0;
        #pragma unroll
        for (int w = 0; w < 16; ++w) { int t = wsum[w]; wsum[w] = run; run += t; }
        bsum[b] = run;
    }
    __syncthreads();
    int incl = wsum[wid] + x;           // block-local inclusive prefix
    if (i < n) offsets[i + 1] = incl;
}

// ---------------- hierarchical scan: part 2 (add block prefix, emit nexta) ----------------
__global__ __launch_bounds__(1024) void scan_fix(const int* __restrict__ counts,
                                                 int* __restrict__ offsets,
                                                 const int* __restrict__ bsum,
                                                 int* __restrict__ nexta, int n) {
    int b = blockIdx.x, tid = threadIdx.x;
    int i = b * 1024 + tid;
    int pre = 0;
    for (int j = 0; j < b; ++j) pre += bsum[j];   // <=19 uniform loads
    if (i == 0) offsets[0] = 0;
    if (i < n) {
        int incl = offsets[i + 1] + pre;
        offsets[i + 1] = incl;
        nexta[i] = incl - counts[i];              // exclusive prefix = scatter cursor
    }
}

// ---------------- counting-sort scatter: emit 8-B records {src, dinv[src]} ----------------
__global__ void scatter_kernel(const int* __restrict__ rowi, const int* __restrict__ coli,
                               const float* __restrict__ dinv,
                               int* __restrict__ nexta, int2* __restrict__ recs, int E) {
    int e = blockIdx.x * blockDim.x + threadIdx.x;
    if (e < E) {
        int c = coli[e];
        int r = rowi[e];
        int pos = atomicAdd(&nexta[c], 1);
        recs[pos] = make_int2(r, __float_as_int(dinv[r]));   // dinv ready (scan ran before)
    }
}

// ---------------- layer-1 aggregation, 2-way channel-sliced ----------------
// xh row-major [n][inc] fp16. Slice s covers channels [s*inc/2, (s+1)*inc/2) — an
// aligned 256-B half-row, so XCD-parity pinning (slice = blockIdx&1, round-robin
// dispatch) halves each L2's working set. Lane owns 2 ch; 4x edge unroll; records
// remove the dependent dinv load. fp32 accum, fp16 out.
__global__ void agg1_f16(const _Float16* __restrict__ xh, const int2* __restrict__ recs,
                         const int* __restrict__ offsets, const float* __restrict__ dinv,
                         _Float16* __restrict__ xout, float* __restrict__ sarr,
                         int inc, int n) {
    int slice = blockIdx.x & 1;
    int gw    = (blockIdx.x >> 1) * 4 + (threadIdx.x >> 6);
    int lane  = threadIdx.x & 63;
    if (gw >= n) return;
    int c   = RL(gw);
    int beg = RL(offsets[c]);
    int end = RL(offsets[c + 1]);
    int coff = slice * (inc >> 1) + lane * 2;             // this lane's channel base
    const _Float16* tab = xh + coff;
    float2 acc = make_float2(0.f, 0.f);
    float wsum = 0.f;
    int i = beg;
    for (; i + 3 < end; i += 4) {
        int2 a0 = recs[i + 0], a1 = recs[i + 1], a2 = recs[i + 2], a3 = recs[i + 3];
        int   r0 = RL(a0.x), r1 = RL(a1.x), r2 = RL(a2.x), r3 = RL(a3.x);
        float w0 = __int_as_float(RL(a0.y)), w1 = __int_as_float(RL(a1.y));
        float w2 = __int_as_float(RL(a2.y)), w3 = __int_as_float(RL(a3.y));
        half2v v0 = *(const half2v*)(tab + (size_t)r0 * inc);
        half2v v1 = *(const half2v*)(tab + (size_t)r1 * inc);
        half2v v2 = *(const half2v*)(tab + (size_t)r2 * inc);
        half2v v3 = *(const half2v*)(tab + (size_t)r3 * inc);
        acc.x = fmaf(w0, (float)v0.x, acc.x); acc.y = fmaf(w0, (float)v0.y, acc.y);
        acc.x = fmaf(w1, (float)v1.x, acc.x); acc.y = fmaf(w1, (float)v1.y, acc.y);
        acc.x = fmaf(w2, (float)v2.x, acc.x); acc.y = fmaf(w2, (float)v2.y, acc.y);
        acc.x = fmaf(w3, (float)v3.x, acc.x); acc.y = fmaf(w3, (float)v3.y, acc.y);
        wsum += w0 + w1 + w2 + w3;
    }
    for (; i < end; ++i) {
        int2 a = recs[i];
        int r = RL(a.x);
        float w = __int_as_float(RL(a.y));
        half2v v = *(const half2v*)(tab + (size_t)r * inc);
        acc.x = fmaf(w, (float)v.x, acc.x); acc.y = fmaf(w, (float)v.y, acc.y);
        wsum += w;
    }
    float dc = dinv[c];
    half2v vc = *(const half2v*)(tab + (size_t)c * inc);
    acc.x = fmaf(dc, (float)vc.x, acc.x); acc.y = fmaf(dc, (float)vc.y, acc.y);
    wsum += dc;
    half2v o;
    o.x = (_Float16)(acc.x * dc); o.y = (_Float16)(acc.y * dc);
    *(half2v*)(xout + (size_t)c * inc + coff) = o;
    if (sarr && slice == 0 && lane == 0) sarr[c] = dc * wsum;   // s = rowsum of A_norm
}

// ---------------- layer-2 aggregation: fp16 gather (128 ch), records, fp32 out ----------------
__global__ void agg2_f16(const _Float16* __restrict__ zh, const int2* __restrict__ recs,
                         const int* __restrict__ offsets, const float* __restrict__ dinv,
                         float* __restrict__ xout, int vpr, int n) {
    int gw   = blockIdx.x * (blockDim.x >> 6) + (threadIdx.x >> 6);
    int lane = threadIdx.x & 63;
    if (gw >= n) return;
    int c   = RL(gw);
    int beg = RL(offsets[c]);
    int end = RL(offsets[c + 1]);
    const half2v* x2 = (const half2v*)zh;
    float2 acc = make_float2(0.f, 0.f);
    int i = beg;
    for (; i + 3 < end; i += 4) {
        int2 a0 = recs[i + 0], a1 = recs[i + 1], a2 = recs[i + 2], a3 = recs[i + 3];
        int   r0 = RL(a0.x), r1 = RL(a1.x), r2 = RL(a2.x), r3 = RL(a3.x);
        float w0 = __int_as_float(RL(a0.y)), w1 = __int_as_float(RL(a1.y));
        float w2 = __int_as_float(RL(a2.y)), w3 = __int_as_float(RL(a3.y));
        half2v v0 = x2[(size_t)r0 * vpr + lane];
        half2v v1 = x2[(size_t)r1 * vpr + lane];
        half2v v2 = x2[(size_t)r2 * vpr + lane];
        half2v v3 = x2[(size_t)r3 * vpr + lane];
        acc.x = fmaf(w0, (float)v0.x, acc.x); acc.y = fmaf(w0, (float)v0.y, acc.y);
        acc.x = fmaf(w1, (float)v1.x, acc.x); acc.y = fmaf(w1, (float)v1.y, acc.y);
        acc.x = fmaf(w2, (float)v2.x, acc.x); acc.y = fmaf(w2, (float)v2.y, acc.y);
        acc.x = fmaf(w3, (float)v3.x, acc.x); acc.y = fmaf(w3, (float)v3.y, acc.y);
    }
    for (; i < end; ++i) {
        int2 a = recs[i];
        int r = RL(a.x);
        float w = __int_as_float(RL(a.y));
        half2v v = x2[(size_t)r * vpr + lane];
        acc.x = fmaf(w, (float)v.x, acc.x); acc.y = fmaf(w, (float)v.y, acc.y);
    }
    float dc = dinv[c];
    half2v vc = x2[(size_t)c * vpr + lane];
    acc.x = fmaf(dc, (float)vc.x, acc.x); acc.y = fmaf(dc, (float)vc.y, acc.y);
    acc.x *= dc; acc.y *= dc;
    ((float2*)xout)[(size_t)c * vpr + lane] = acc;
}

// ---------------- fp16 MFMA GEMM: C = A@B (+ bias or s*bias) (+relu), fp16 out ----------------
// A: MxK f16 row-major.  BT: NxK f16 row-major.  C: MxN f16 row-major.
template<int BM, int BN, bool RELU, bool SBIAS>
__global__ __launch_bounds__(256) void gemm_mfma(
        const _Float16* __restrict__ A, const _Float16* __restrict__ BT,
        const float* __restrict__ bias, const float* __restrict__ sarr,
        _Float16* __restrict__ C, int M, int K, int N) {
    constexpr int FM = BM / 2 / 16, FN = BN / 2 / 16;
    constexpr int APT = BM * 4 / 256, BPT = BN * 4 / 256;   // 16B granules per thread
    static_assert(BM % 32 == 0 && BN % 32 == 0, "wave tile divisibility");
    __shared__ unsigned short A_lds[BM * 40];   // 80 B per 32-half row (2-way bank aliasing, free)
    __shared__ unsigned short B_lds[BN * 40];
    int tid  = threadIdx.x;
    int wid  = tid >> 6, lane = tid & 63;
    int wm   = wid >> 1, wn = wid & 1;
    int q    = lane >> 4, r = lane & 15;
    int m0   = blockIdx.x * BM, n0 = blockIdx.y * BN;

    f32x4 acc[FM][FN];
    #pragma unroll
    for (int i = 0; i < FM; ++i)
        #pragma unroll
        for (int j = 0; j < FN; ++j)
            acc[i][j] = (f32x4){0.f, 0.f, 0.f, 0.f};

    ushort8v areg[APT], breg[BPT];
    auto loadA = [&](int k0) {
        #pragma unroll
        for (int i = 0; i < APT; ++i) {
            int g = tid + i * 256;
            int row = g >> 2, slot = g & 3;
            int gm = m0 + row;
            if (gm < M) areg[i] = *(const ushort8v*)(A + (size_t)gm * K + k0 + slot * 8);
            else        areg[i] = (ushort8v){0,0,0,0,0,0,0,0};
        }
    };
    auto loadB = [&](int k0) {
        #pragma unroll
        for (int i = 0; i < BPT; ++i) {
            int g = tid + i * 256;
            int row = g >> 2, slot = g & 3;
            breg[i] = *(const ushort8v*)(BT + (size_t)(n0 + row) * K + k0 + slot * 8);
        }
    };

    loadA(0); loadB(0);
    int steps = K / 32;
    for (int s = 0; s < steps; ++s) {
        __syncthreads();
        #pragma unroll
        for (int i = 0; i < APT; ++i) {
            int g = tid + i * 256;
            *(ushort8v*)&A_lds[(g >> 2) * 40 + (g & 3) * 8] = areg[i];
        }
        #pragma unroll
        for (int i = 0; i < BPT; ++i) {
            int g = tid + i * 256;
            *(ushort8v*)&B_lds[(g >> 2) * 40 + (g & 3) * 8] = breg[i];
        }
        __syncthreads();
        if (s + 1 < steps) { loadA((s + 1) * 32); loadB((s + 1) * 32); }
        f16x8 af[FM], bf[FN];
        #pragma unroll
        for (int i = 0; i < FM; ++i)
            af[i] = *(const f16x8*)&A_lds[(wm * (BM / 2) + i * 16 + r) * 40 + q * 8];
        #pragma unroll
        for (int j = 0; j < FN; ++j)
            bf[j] = *(const f16x8*)&B_lds[(wn * (BN / 2) + j * 16 + r) * 40 + q * 8];
        #pragma unroll
        for (int i = 0; i < FM; ++i)
            #pragma unroll
            for (int j = 0; j < FN; ++j)
                acc[i][j] = __builtin_amdgcn_mfma_f32_16x16x32_f16(af[i], bf[j], acc[i][j], 0, 0, 0);
    }

    // epilogue: D row = q*4+reg, col = r (m89-verified layout)
    #pragma unroll
    for (int i = 0; i < FM; ++i) {
        int row_base = m0 + wm * (BM / 2) + i * 16 + q * 4;
        #pragma unroll
        for (int g = 0; g < 4; ++g) {
            int row = row_base + g;
            if (row >= M) continue;
            float sv = SBIAS ? sarr[row] : 1.f;
            #pragma unroll
            for (int j = 0; j < FN; ++j) {
                int col = n0 + wn * (BN / 2) + j * 16 + r;
                float v = acc[i][j][g] + sv * bias[col];
                if (RELU) v = fmaxf(v, 0.f);
                C[(size_t)row * N + col] = (_Float16)v;
            }
        }
    }
}

extern "C" void kernel_launch(void* const* d_in, const int* in_sizes, int n_in,
                              void* d_out, int out_size, void* d_ws, size_t ws_size,
                              hipStream_t stream) {
    const float* x  = (const float*)d_in[0];
    const int*   ei = (const int*)d_in[1];
    const float* W1 = (const float*)d_in[2];
    const float* b1 = (const float*)d_in[3];
    const float* W2 = (const float*)d_in[4];
    const float* b2 = (const float*)d_in[5];

    const int hid  = in_sizes[3];             // 512
    const int outc = in_sizes[5];             // 128
    const int inc  = in_sizes[2] / hid;       // 256
    const int n    = in_sizes[0] / inc;       // 20000
    const int E    = in_sizes[1] / 2;         // 640000
    const int* rowi = ei;                     // edge_index[0] = sources
    const int* coli = ei + E;                 // edge_index[1] = destinations

    char* p = (char*)d_ws;
    auto carve = [&](size_t bytes) {
        char* q = p;
        p += (bytes + 255) & ~(size_t)255;
        return (void*)q;
    };
    int*      counts  = (int*)     carve((size_t)n * 4);
    int*      offsets = (int*)     carve((size_t)(n + 1) * 4);
    int*      nexta   = (int*)     carve((size_t)n * 4);
    int2*     recs    = (int2*)    carve((size_t)(E + 8) * 8);   // {src, dinv[src]} records
    float*    dinv    = (float*)   carve((size_t)n * 4);
    float*    sarr    = (float*)   carve((size_t)n * 4);
    int*      bsum    = (int*)     carve((size_t)32 * 4);
    _Float16* xh      = (_Float16*)carve((size_t)n * inc * 2);   // fp16 x row-major (reused as zh)
    _Float16* aggxh   = (_Float16*)carve((size_t)n * inc * 2);   // fp16 A@x row-major
    _Float16* hh      = (_Float16*)carve((size_t)n * hid * 2);   // fp16 hidden row-major
    _Float16* w1t     = (_Float16*)carve((size_t)inc * hid * 2); // fp16 W1^T [hid][inc]
    _Float16* w2t     = (_Float16*)carve((size_t)hid * outc * 2);// fp16 W2^T [outc][hid]
    _Float16* zh      = xh;                                       // alias: xh dead after agg1

    const int SCAN_B = CDIV(n, 1024);
    const int PREP_T = n * inc / 8 + inc * hid + hid * outc + n;

    prep_kernel<<<CDIV(PREP_T, 256), 256, 0, stream>>>(x, xh, W1, w1t, W2, w2t, counts,
                                                       n, inc, hid, outc);
    hist_kernel<<<CDIV(E, 256), 256, 0, stream>>>(coli, counts, E);
    scan_part<<<SCAN_B, 1024, 0, stream>>>(counts, offsets, bsum, dinv, n);
    scan_fix<<<SCAN_B, 1024, 0, stream>>>(counts, offsets, bsum, nexta, n);
    scatter_kernel<<<CDIV(E, 256), 256, 0, stream>>>(rowi, coli, dinv, nexta, recs, E);

    // layer 1: h = relu((A@x) @ W1 + s*b1); agg1 2-way sliced (slice = blockIdx&1 -> XCD parity)
    agg1_f16<<<CDIV(n, 4) * 2, 256, 0, stream>>>(xh, recs, offsets, dinv, aggxh, sarr, inc, n);
    dim3 g1(CDIV(n, 128), hid / 128);
    gemm_mfma<128, 128, true, true><<<g1, 256, 0, stream>>>(aggxh, w1t, b1, sarr, hh, n, inc, hid);

    // layer 2: out = A@(h @ W2 + b2)
    dim3 g2(CDIV(n, 64), outc / 128);
    gemm_mfma<64, 128, false, false><<<g2, 256, 0, stream>>>(hh, w2t, b2, nullptr, zh, n, hid, outc);
    agg2_f16<<<CDIV(n, 4), 256, 0, stream>>>(zh, recs, offsets, dinv, (float*)d_out, outc / 2, n);
}